// Round 15
// baseline (645.224 us; speedup 1.0000x reference)
//
#include <hip/hip_runtime.h>

constexpr int BN = 512;
constexpr int NITER = 50;

#define CEXP  (-28.853900817779268f)  /* -log2(e)/0.05 */
#define ESH   (14.0f)                 /* E' = 2^(M*CEXP + 14) in fp16 */
#define L2TAU (9.965784284662087f)    /* log2(1000) */
#define TAU_U (1000.0f)               /* |u| threshold (linear) */
#define TAU_V (0.06103515625f)        /* 1000 * 2^-14 (linear, on pbh*qr) */

typedef unsigned int u32;

__device__ __forceinline__ float fexp2(float x) { return __builtin_amdgcn_exp2f(x); }
__device__ __forceinline__ float flog2(float x) { return __builtin_amdgcn_logf(x); }
__device__ __forceinline__ float frcp(float x)  { return __builtin_amdgcn_rcpf(x); }

__device__ __forceinline__ float nr_rcp(float x) {
    float r = frcp(x);
    return fmaf(r, fmaf(-x, r, 1.0f), r);
}

template <int CTRL>
__device__ __forceinline__ float dppx(float x) {
    return __int_as_float(__builtin_amdgcn_update_dpp(
        0, __float_as_int(x), CTRL, 0xF, 0xF, true));
}

__device__ __forceinline__ float bfly_sum(float x) {
    x += dppx<0xB1>(x);            // xor1 (quad_perm)
    x += dppx<0x4E>(x);            // xor2 (quad_perm)
    x += dppx<0x141>(x);           // xor4 (half_mirror)
    x += dppx<0x140>(x);           // xor8 (mirror)
    x += __shfl_xor(x, 16, 64);
    x += __shfl_xor(x, 32, 64);
    return x;
}
__device__ __forceinline__ float bfly_max(float x) {
    x = fmaxf(x, dppx<0xB1>(x));
    x = fmaxf(x, dppx<0x4E>(x));
    x = fmaxf(x, dppx<0x141>(x));
    x = fmaxf(x, dppx<0x140>(x));
    x = fmaxf(x, __shfl_xor(x, 16, 64));
    x = fmaxf(x, __shfl_xor(x, 32, 64));
    return x;
}

// accLo += f16lo(e2)*pLo ; accHi += f16hi(e2)*pHi  (one VALU op each)
__device__ __forceinline__ void fma_mix2(float& accLo, float& accHi, u32 e2,
                                         float pLo, float pHi) {
    asm("v_fma_mix_f32 %0, %2, %3, %0 op_sel_hi:[1,0,0]\n\t"
        "v_fma_mix_f32 %1, %2, %4, %1 op_sel:[1,0,0] op_sel_hi:[1,0,0]"
        : "+v"(accLo), "+v"(accHi)
        : "v"(e2), "v"(pLo), "v"(pHi));
}

// barrier draining LDS ops only — keeps global register-prefetch loads in flight
__device__ __forceinline__ void barrier_lgkm() {
    asm volatile("s_waitcnt lgkmcnt(0)\n\ts_barrier" ::: "memory");
}

// ---------------- Kernel A: E' = fp16(2^(M*CEXP+14)), stored transposed ----------------
__global__ __launch_bounds__(256)
void prep_exp_t(const float* __restrict__ X, float* __restrict__ out)
{
    const int blk  = blockIdx.x;
    const int b    = blk >> 4;
    const int tile = blk & 15;
    const int i0   = (tile >> 2) << 7;
    const int j0   = (tile & 3) << 7;
    const int tid  = threadIdx.x;

    const float* __restrict__ Mb = X + (size_t)b * (BN * BN);
    _Float16* __restrict__ Et = reinterpret_cast<_Float16*>(out + (size_t)b * (BN * BN));

    __shared__ _Float16 T[128][130];

    #pragma unroll
    for (int k = 0; k < 16; ++k) {
        int idx = tid + (k << 8);
        int fi  = idx >> 5;
        int fj  = idx & 31;
        float4 m = *reinterpret_cast<const float4*>(Mb + (size_t)(i0 + fi) * BN + j0 + (fj << 2));
        T[(fj << 2) + 0][fi] = (_Float16)fexp2(fmaf(m.x, CEXP, ESH));
        T[(fj << 2) + 1][fi] = (_Float16)fexp2(fmaf(m.y, CEXP, ESH));
        T[(fj << 2) + 2][fi] = (_Float16)fexp2(fmaf(m.z, CEXP, ESH));
        T[(fj << 2) + 3][fi] = (_Float16)fexp2(fmaf(m.w, CEXP, ESH));
    }
    __syncthreads();
    #pragma unroll
    for (int k = 0; k < 32; ++k) {
        int o  = tid + (k << 8);
        int j  = o >> 6;
        int c2 = o & 63;
        u32 val = *reinterpret_cast<const u32*>(&T[j][c2 << 1]);
        *reinterpret_cast<u32*>(Et + (size_t)(j0 + j) * BN + i0 + (c2 << 1)) = val;
    }
}

// ---------------- consume4 v3: linear-domain, rcp-only, no logs/NR/scales ----------------
__device__ __forceinline__ void consume4v3(
    uint4 c0, uint4 c1, uint4 c2, uint4 c3, int jb,
    float pr0, float pr1, float pr2, float pr3,
    float pr4, float pr5, float pr6, float pr7,
    float& a0, float& a1, float& a2, float& a3,
    float& a4, float& a5, float& a6, float& a7,
    float& vml, const float* pbh, float* qv, int lane)
{
    const float4 pb4 = *reinterpret_cast<const float4*>(&pbh[jb]);

    float s00 = 0.f, s01 = 0.f;
    fma_mix2(s00, s01, c0.x, pr0, pr1); fma_mix2(s00, s01, c0.y, pr2, pr3);
    fma_mix2(s00, s01, c0.z, pr4, pr5); fma_mix2(s00, s01, c0.w, pr6, pr7);
    float s10 = 0.f, s11 = 0.f;
    fma_mix2(s10, s11, c1.x, pr0, pr1); fma_mix2(s10, s11, c1.y, pr2, pr3);
    fma_mix2(s10, s11, c1.z, pr4, pr5); fma_mix2(s10, s11, c1.w, pr6, pr7);
    float s20 = 0.f, s21 = 0.f;
    fma_mix2(s20, s21, c2.x, pr0, pr1); fma_mix2(s20, s21, c2.y, pr2, pr3);
    fma_mix2(s20, s21, c2.z, pr4, pr5); fma_mix2(s20, s21, c2.w, pr6, pr7);
    float s30 = 0.f, s31 = 0.f;
    fma_mix2(s30, s31, c3.x, pr0, pr1); fma_mix2(s30, s31, c3.y, pr2, pr3);
    fma_mix2(s30, s31, c3.z, pr4, pr5); fma_mix2(s30, s31, c3.w, pr6, pr7);

    float r0 = bfly_sum(s00 + s01);
    float r1 = bfly_sum(s10 + s11);
    float r2 = bfly_sum(s20 + s21);
    float r3 = bfly_sum(s30 + s31);

    // qr_j = 1/S_j  (raw: carries the 2^-14 and 2^-beta scales implicitly)
    float q0 = frcp(r0), q1 = frcp(r1), q2 = frcp(r2), q3 = frcp(r3);

    // |v_j| * 2^-14 = pbh_j * qr_j  -> linear absorb check vs TAU_V
    vml = fmaxf(vml, fmaxf(fmaxf(pb4.x * q0, pb4.y * q1),
                           fmaxf(pb4.z * q2, pb4.w * q3)));
    if (lane == 0)
        *reinterpret_cast<float4*>(&qv[jb]) = make_float4(q0, q1, q2, q3);

    fma_mix2(a0, a1, c0.x, q0, q0); fma_mix2(a2, a3, c0.y, q0, q0);
    fma_mix2(a4, a5, c0.z, q0, q0); fma_mix2(a6, a7, c0.w, q0, q0);
    fma_mix2(a0, a1, c1.x, q1, q1); fma_mix2(a2, a3, c1.y, q1, q1);
    fma_mix2(a4, a5, c1.z, q1, q1); fma_mix2(a6, a7, c1.w, q1, q1);
    fma_mix2(a0, a1, c2.x, q2, q2); fma_mix2(a2, a3, c2.y, q2, q2);
    fma_mix2(a4, a5, c2.z, q2, q2); fma_mix2(a6, a7, c2.w, q2, q2);
    fma_mix2(a0, a1, c3.x, q3, q3); fma_mix2(a2, a3, c3.y, q3, q3);
    fma_mix2(a4, a5, c3.z, q3, q3); fma_mix2(a6, a7, c3.w, q3, q3);
}

// ---------------- Kernel B v3: R10 shape + linear domain + 2 barriers ----------------
// Invariants: pv = 2^alpha * u (raw p);  2^14 * qv = 2^beta * v;  pah=2^-alpha; pbh=2^-beta.
__global__ __launch_bounds__(512)
__attribute__((amdgpu_waves_per_eu(2, 2)))
void sinkhorn_v3(const float* __restrict__ X, float* __restrict__ out,
                 float* __restrict__ cucv)
{
    const int b    = blockIdx.x;
    const int t    = threadIdx.x;      // 0..511
    const int lane = t & 63;
    const int w    = t >> 6;           // 0..7

    const u32* __restrict__ Et4 =
        reinterpret_cast<const u32*>(out + (size_t)b * (BN * BN));

    __shared__ float pah[BN], pbh[BN], pv[BN], qv[BN];   // 8 KB
    __shared__ float tpart[8][BN];                       // 16 KB
    __shared__ float wmaxlu[8], wmaxlv[2][8];
    __shared__ uint4 stage[8][16][64];                   // 128 KB -> 1 block/CU

    pah[t] = 1.0f; pbh[t] = 1.0f;
    pv[t]  = 0x1p-9f; qv[t] = 0x1p-23f;   // qv init never read (overwritten each iter)

    const int jb0 = w << 6;            // 64 columns per wave
    const u32* gbase = Et4 + (size_t)jb0 * 256 + (lane << 2);
#define LD(c) (*reinterpret_cast<const uint4*>(gbase + (size_t)(c) * 256))

    // static stage: cols jb0+48..jb0+63 (iteration-invariant, wave-private)
    #pragma unroll
    for (int c = 0; c < 16; ++c)
        stage[w][c][lane] = LD(48 + c);

    // proven 4-slot ring, 3-group lookahead
    uint4 e0 = LD(0),  e1 = LD(1),  e2 = LD(2),  e3 = LD(3);
    uint4 f0 = LD(4),  f1 = LD(5),  f2 = LD(6),  f3 = LD(7);
    uint4 h0 = LD(8),  h1 = LD(9),  h2 = LD(10), h3 = LD(11);
    uint4 k0, k1, k2, k3;

    __syncthreads();

    for (int it = 0; it < NITER; ++it) {
        const float4 prA = *reinterpret_cast<const float4*>(&pv[lane * 8]);
        const float4 prB = *reinterpret_cast<const float4*>(&pv[lane * 8 + 4]);
        const float pr0 = prA.x, pr1 = prA.y, pr2 = prA.z, pr3 = prA.w;
        const float pr4 = prB.x, pr5 = prB.y, pr6 = prB.z, pr7 = prB.w;

        float a0 = 0.f, a1 = 0.f, a2 = 0.f, a3 = 0.f;
        float a4 = 0.f, a5 = 0.f, a6 = 0.f, a7 = 0.f;
        float vml = 0.0f;

#define STEP(B0,B1,B2,B3, I0,I1,I2,I3, ICOL, JOFF)                            \
        I0 = LD((ICOL) + 0); I1 = LD((ICOL) + 1);                             \
        I2 = LD((ICOL) + 2); I3 = LD((ICOL) + 3);                             \
        consume4v3(B0, B1, B2, B3, jb0 + (JOFF),                              \
                   pr0, pr1, pr2, pr3, pr4, pr5, pr6, pr7,                    \
                   a0, a1, a2, a3, a4, a5, a6, a7, vml, pbh, qv, lane);

        STEP(e0,e1,e2,e3, k0,k1,k2,k3, 12,  0)
        STEP(f0,f1,f2,f3, e0,e1,e2,e3, 16,  4)
        STEP(h0,h1,h2,h3, f0,f1,f2,f3, 20,  8)
        STEP(k0,k1,k2,k3, h0,h1,h2,h3, 24, 12)
        STEP(e0,e1,e2,e3, k0,k1,k2,k3, 28, 16)
        STEP(f0,f1,f2,f3, e0,e1,e2,e3, 32, 20)
        STEP(h0,h1,h2,h3, f0,f1,f2,f3, 36, 24)
        STEP(k0,k1,k2,k3, h0,h1,h2,h3, 40, 28)
        STEP(e0,e1,e2,e3, k0,k1,k2,k3, 44, 32)
        STEP(f0,f1,f2,f3, e0,e1,e2,e3,  0, 36)
        STEP(h0,h1,h2,h3, f0,f1,f2,f3,  4, 40)
        STEP(k0,k1,k2,k3, h0,h1,h2,h3,  8, 44)
#undef STEP

        // 4 LDS groups: cols 48..63
        #pragma unroll
        for (int ls = 0; ls < 4; ++ls) {
            uint4 l0v = stage[w][ls * 4 + 0][lane];
            uint4 l1v = stage[w][ls * 4 + 1][lane];
            uint4 l2v = stage[w][ls * 4 + 2][lane];
            uint4 l3v = stage[w][ls * 4 + 3][lane];
            consume4v3(l0v, l1v, l2v, l3v, jb0 + 48 + ls * 4,
                       pr0, pr1, pr2, pr3, pr4, pr5, pr6, pr7,
                       a0, a1, a2, a3, a4, a5, a6, a7, vml, pbh, qv, lane);
        }

        *reinterpret_cast<float4*>(&tpart[w][lane * 8]) = make_float4(a0, a1, a2, a3);
        *reinterpret_cast<float4*>(&tpart[w][lane * 8 + 4]) = make_float4(a4, a5, a6, a7);
        if (lane == 0) wmaxlv[it & 1][w] = vml;
        barrier_lgkm();                               // barrier 1

        // ---- fold: raw t, optimistic pv, linear |u| check ----
        float p0 = 0, p1 = 0, p2 = 0, p3 = 0;
        #pragma unroll
        for (int w2 = 0; w2 < 8; w2 += 4) {
            p0 += tpart[w2 + 0][t];
            p1 += tpart[w2 + 1][t];
            p2 += tpart[w2 + 2][t];
            p3 += tpart[w2 + 3][t];
        }
        float tt  = (p0 + p1) + (p2 + p3);
        float pvn = frcp(tt);                         // p_new = 1/t (raw)
        float ul  = pah[t] * pvn;                     // |u|
        float m   = bfly_max(ul);
        pv[t] = pvn;                                  // optimistic (common case)
        if (lane == 0) wmaxlu[w] = m;
        barrier_lgkm();                               // barrier 2

        float mlu = wmaxlu[0], mlv = wmaxlv[it & 1][0];
        #pragma unroll
        for (int i2 = 1; i2 < 8; ++i2) {
            mlu = fmaxf(mlu, wmaxlu[i2]);
            mlv = fmaxf(mlv, wmaxlv[it & 1][i2]);
        }
        if (mlu > TAU_U || mlv > TAU_V) {             // block-uniform, rare
            pah[t] = frcp(pvn);                       // 2^-alpha_new = 1/p
            pv[t]  = pvn * 0x1p-9f;                   // p = 2^alpha_new / N
            float qo = qv[t];
            pbh[t] = 0x1p-14f * frcp(qo);             // 2^-beta_new = 2^-14/qr
            qv[t]  = qo * 0x1p-9f;                    // keep 2^14 q = 2^beta v with v=1/N
            barrier_lgkm();                           // barrier 3 (absorb only)
        }
    }
#undef LD

    // cu = log2(p); cv = 14 + log2(qr)
    cucv[(size_t)b * 1024 + t]       = flog2(pv[t]);
    cucv[(size_t)b * 1024 + 512 + t] = 14.0f + flog2(qv[t]);
}

// ---------------- consume4 v1 + fallback kernel: R10-proven verbatim ----------------
__device__ __forceinline__ void consume4(
    uint4 c0, uint4 c1, uint4 c2, uint4 c3, int jb,
    float pr0, float pr1, float pr2, float pr3,
    float pr4, float pr5, float pr6, float pr7,
    float& a0, float& a1, float& a2, float& a3,
    float& a4, float& a5, float& a6, float& a7,
    float& vml, const float* bh, float* lv, int lane)
{
    const float4 bh4 = *reinterpret_cast<const float4*>(&bh[jb]);

    float s00 = 0.f, s01 = 0.f;
    fma_mix2(s00, s01, c0.x, pr0, pr1); fma_mix2(s00, s01, c0.y, pr2, pr3);
    fma_mix2(s00, s01, c0.z, pr4, pr5); fma_mix2(s00, s01, c0.w, pr6, pr7);
    float s10 = 0.f, s11 = 0.f;
    fma_mix2(s10, s11, c1.x, pr0, pr1); fma_mix2(s10, s11, c1.y, pr2, pr3);
    fma_mix2(s10, s11, c1.z, pr4, pr5); fma_mix2(s10, s11, c1.w, pr6, pr7);
    float s20 = 0.f, s21 = 0.f;
    fma_mix2(s20, s21, c2.x, pr0, pr1); fma_mix2(s20, s21, c2.y, pr2, pr3);
    fma_mix2(s20, s21, c2.z, pr4, pr5); fma_mix2(s20, s21, c2.w, pr6, pr7);
    float s30 = 0.f, s31 = 0.f;
    fma_mix2(s30, s31, c3.x, pr0, pr1); fma_mix2(s30, s31, c3.y, pr2, pr3);
    fma_mix2(s30, s31, c3.z, pr4, pr5); fma_mix2(s30, s31, c3.w, pr6, pr7);

    float r0 = bfly_sum(s00 + s01);
    float r1 = bfly_sum(s10 + s11);
    float r2 = bfly_sum(s20 + s21);
    float r3 = bfly_sum(s30 + s31);

    float t0 = r0 * 0x1p-14f, t1 = r1 * 0x1p-14f;
    float t2 = r2 * 0x1p-14f, t3 = r3 * 0x1p-14f;
    float q0 = nr_rcp(t0), q1 = nr_rcp(t1), q2 = nr_rcp(t2), q3 = nr_rcp(t3);
    float l0 = -bh4.x - flog2(t0), l1 = -bh4.y - flog2(t1);
    float l2 = -bh4.z - flog2(t2), l3 = -bh4.w - flog2(t3);
    vml = fmaxf(vml, fmaxf(fmaxf(l0, l1), fmaxf(l2, l3)));
    if (lane == 0)
        *reinterpret_cast<float4*>(&lv[jb]) = make_float4(l0, l1, l2, l3);

    fma_mix2(a0, a1, c0.x, q0, q0); fma_mix2(a2, a3, c0.y, q0, q0);
    fma_mix2(a4, a5, c0.z, q0, q0); fma_mix2(a6, a7, c0.w, q0, q0);
    fma_mix2(a0, a1, c1.x, q1, q1); fma_mix2(a2, a3, c1.y, q1, q1);
    fma_mix2(a4, a5, c1.z, q1, q1); fma_mix2(a6, a7, c1.w, q1, q1);
    fma_mix2(a0, a1, c2.x, q2, q2); fma_mix2(a2, a3, c2.y, q2, q2);
    fma_mix2(a4, a5, c2.z, q2, q2); fma_mix2(a6, a7, c2.w, q2, q2);
    fma_mix2(a0, a1, c3.x, q3, q3); fma_mix2(a2, a3, c3.y, q3, q3);
    fma_mix2(a4, a5, c3.z, q3, q3); fma_mix2(a6, a7, c3.w, q3, q3);
}

__global__ __launch_bounds__(512)
__attribute__((amdgpu_waves_per_eu(2, 2)))
void sinkhorn_w512(const float* __restrict__ X, float* __restrict__ out,
                   float* __restrict__ cucv)
{
    const int b    = blockIdx.x;
    const int t    = threadIdx.x;
    const int lane = t & 63;
    const int w    = t >> 6;

    const u32* __restrict__ Et4 =
        reinterpret_cast<const u32*>(out + (size_t)b * (BN * BN));

    __shared__ float ah[BN], bh[BN], lu[BN], lv[BN], pv[BN];
    __shared__ float tpart[8][BN];
    __shared__ float wmaxlu[8], wmaxlv[8];
    __shared__ uint4 stage[8][16][64];

    ah[t] = 0.f; bh[t] = 0.f;
    lu[t] = -9.f; lv[t] = -9.f;
    pv[t] = 0x1p-9f;

    const int jb0 = w << 6;
    const u32* gbase = Et4 + (size_t)jb0 * 256 + (lane << 2);
#define LD(c) (*reinterpret_cast<const uint4*>(gbase + (size_t)(c) * 256))

    #pragma unroll
    for (int c = 0; c < 16; ++c)
        stage[w][c][lane] = LD(48 + c);

    uint4 e0 = LD(0),  e1 = LD(1),  e2 = LD(2),  e3 = LD(3);
    uint4 f0 = LD(4),  f1 = LD(5),  f2 = LD(6),  f3 = LD(7);
    uint4 h0 = LD(8),  h1 = LD(9),  h2 = LD(10), h3 = LD(11);
    uint4 k0, k1, k2, k3;

    __syncthreads();

    for (int it = 0; it < NITER; ++it) {
        const float4 prA = *reinterpret_cast<const float4*>(&pv[lane * 8]);
        const float4 prB = *reinterpret_cast<const float4*>(&pv[lane * 8 + 4]);
        const float pr0 = prA.x, pr1 = prA.y, pr2 = prA.z, pr3 = prA.w;
        const float pr4 = prB.x, pr5 = prB.y, pr6 = prB.z, pr7 = prB.w;

        float a0 = 0.f, a1 = 0.f, a2 = 0.f, a3 = 0.f;
        float a4 = 0.f, a5 = 0.f, a6 = 0.f, a7 = 0.f;
        float vml = -1e30f;

#define STEP(B0,B1,B2,B3, I0,I1,I2,I3, ICOL, JOFF)                            \
        I0 = LD((ICOL) + 0); I1 = LD((ICOL) + 1);                             \
        I2 = LD((ICOL) + 2); I3 = LD((ICOL) + 3);                             \
        consume4(B0, B1, B2, B3, jb0 + (JOFF),                                \
                 pr0, pr1, pr2, pr3, pr4, pr5, pr6, pr7,                      \
                 a0, a1, a2, a3, a4, a5, a6, a7, vml, bh, lv, lane);

        STEP(e0,e1,e2,e3, k0,k1,k2,k3, 12,  0)
        STEP(f0,f1,f2,f3, e0,e1,e2,e3, 16,  4)
        STEP(h0,h1,h2,h3, f0,f1,f2,f3, 20,  8)
        STEP(k0,k1,k2,k3, h0,h1,h2,h3, 24, 12)
        STEP(e0,e1,e2,e3, k0,k1,k2,k3, 28, 16)
        STEP(f0,f1,f2,f3, e0,e1,e2,e3, 32, 20)
        STEP(h0,h1,h2,h3, f0,f1,f2,f3, 36, 24)
        STEP(k0,k1,k2,k3, h0,h1,h2,h3, 40, 28)
        STEP(e0,e1,e2,e3, k0,k1,k2,k3, 44, 32)
        STEP(f0,f1,f2,f3, e0,e1,e2,e3,  0, 36)
        STEP(h0,h1,h2,h3, f0,f1,f2,f3,  4, 40)
        STEP(k0,k1,k2,k3, h0,h1,h2,h3,  8, 44)
#undef STEP

        #pragma unroll
        for (int ls = 0; ls < 4; ++ls) {
            uint4 l0v = stage[w][ls * 4 + 0][lane];
            uint4 l1v = stage[w][ls * 4 + 1][lane];
            uint4 l2v = stage[w][ls * 4 + 2][lane];
            uint4 l3v = stage[w][ls * 4 + 3][lane];
            consume4(l0v, l1v, l2v, l3v, jb0 + 48 + ls * 4,
                     pr0, pr1, pr2, pr3, pr4, pr5, pr6, pr7,
                     a0, a1, a2, a3, a4, a5, a6, a7, vml, bh, lv, lane);
        }

        *reinterpret_cast<float4*>(&tpart[w][lane * 8]) = make_float4(a0, a1, a2, a3);
        *reinterpret_cast<float4*>(&tpart[w][lane * 8 + 4]) = make_float4(a4, a5, a6, a7);
        if (lane == 0) wmaxlv[w] = vml;
        barrier_lgkm();

        float p0 = 0, p1 = 0, p2 = 0, p3 = 0;
        #pragma unroll
        for (int w2 = 0; w2 < 8; w2 += 4) {
            p0 += tpart[w2 + 0][t];
            p1 += tpart[w2 + 1][t];
            p2 += tpart[w2 + 2][t];
            p3 += tpart[w2 + 3][t];
        }
        float tt  = ((p0 + p1) + (p2 + p3)) * 0x1p-14f;
        float lun = -ah[t] - flog2(tt);
        float m = bfly_max(lun);
        if (lane == 0) wmaxlu[w] = m;
        barrier_lgkm();

        float mlu = wmaxlu[0], mlv = wmaxlv[0];
        #pragma unroll
        for (int i2 = 1; i2 < 8; ++i2) {
            mlu = fmaxf(mlu, wmaxlu[i2]);
            mlv = fmaxf(mlv, wmaxlv[i2]);
        }
        if (mlu > L2TAU || mlv > L2TAU) {
            float an = ah[t] + lun;
            ah[t] = an;
            lu[t] = -9.f;
            pv[t] = fexp2(an - 9.0f);
            bh[t] += lv[t];
            lv[t] = -9.f;
        } else {
            lu[t] = lun;
            pv[t] = nr_rcp(tt);
        }
        barrier_lgkm();
    }
#undef LD

    cucv[(size_t)b * 1024 + t]       = ah[t] + lu[t];
    cucv[(size_t)b * 1024 + 512 + t] = bh[t] + lv[t];
}

// ---------------- Kernel C: Gamma epilogue on the full chip ----------------
__global__ __launch_bounds__(256)
void gamma_out(const float* __restrict__ X, float* __restrict__ out,
               const float* __restrict__ cucv)
{
    const int blk  = blockIdx.x;
    const int b    = blk >> 4;
    const int tile = blk & 15;
    const int tid  = threadIdx.x;
    const int i0   = tile << 5;

    __shared__ float cu[32];
    __shared__ float cv[BN];

    if (tid < 32) cu[tid] = cucv[(size_t)b * 1024 + i0 + tid];
    cv[tid]        = cucv[(size_t)b * 1024 + 512 + tid];
    cv[tid + 256]  = cucv[(size_t)b * 1024 + 768 + tid];
    __syncthreads();

    const float* __restrict__ Mb = X + (size_t)b * (BN * BN);
    float* __restrict__ Gb = out + (size_t)b * (BN * BN);
    const float4* __restrict__ cv4 = reinterpret_cast<const float4*>(cv);

    #pragma unroll
    for (int k = 0; k < 16; ++k) {
        int idx = tid + (k << 8);
        int r   = idx >> 7;
        int c4  = idx & 127;
        int i   = i0 + r;
        float4 m = *reinterpret_cast<const float4*>(Mb + (size_t)i * BN + (c4 << 2));
        float4 c = cv4[c4];
        float cui = cu[r];
        float4 g;
        g.x = fexp2(fmaf(m.x, CEXP, cui + c.x));
        g.y = fexp2(fmaf(m.y, CEXP, cui + c.y));
        g.z = fexp2(fmaf(m.z, CEXP, cui + c.z));
        g.w = fexp2(fmaf(m.w, CEXP, cui + c.w));
        *reinterpret_cast<float4*>(Gb + (size_t)i * BN + (c4 << 2)) = g;
    }
}

extern "C" void kernel_launch(void* const* d_in, const int* in_sizes, int n_in,
                              void* d_out, int out_size, void* d_ws, size_t ws_size,
                              hipStream_t stream)
{
    const float* X = (const float*)d_in[0];
    float* out = (float*)d_out;
    const int batch = in_sizes[0] / (BN * BN);   // 128

    prep_exp_t<<<batch * 16, 256, 0, stream>>>(X, out);

    // spill guard ONLY: scratch-free v3 is safe at any register count.
    // (R13's numRegs>=96 clause wrongly rejected the leaner kernel.)
    bool v3_ok = false;
    hipFuncAttributes fa{};
    if (hipFuncGetAttributes(&fa, (const void*)sinkhorn_v3) == hipSuccess)
        v3_ok = (fa.localSizeBytes == 0);

    float* cucv = (float*)d_ws;
    if (v3_ok)
        sinkhorn_v3<<<batch, 512, 0, stream>>>(X, out, cucv);
    else
        sinkhorn_w512<<<batch, 512, 0, stream>>>(X, out, cucv);
    gamma_out<<<batch * 16, 256, 0, stream>>>(X, out, cucv);
}

// Round 16
// 639.153 us; speedup vs baseline: 1.0095x; 1.0095x over previous
//
#include <hip/hip_runtime.h>

constexpr int BN = 512;
constexpr int NITER = 50;

#define CEXP  (-28.853900817779268f)  /* -log2(e)/0.05 */
#define ESH   (14.0f)                 /* E' = 2^(M*CEXP + 14) in fp16 */
#define L2TAU (9.965784284662087f)    /* log2(1000) */
#define TAU_U (1000.0f)               /* |u| threshold (linear) */
#define TAU_V (0.06103515625f)        /* 1000 * 2^-14 (linear, on pbh*qr) */

typedef unsigned int u32;

__device__ __forceinline__ float fexp2(float x) { return __builtin_amdgcn_exp2f(x); }
__device__ __forceinline__ float flog2(float x) { return __builtin_amdgcn_logf(x); }
__device__ __forceinline__ float frcp(float x)  { return __builtin_amdgcn_rcpf(x); }

__device__ __forceinline__ float nr_rcp(float x) {
    float r = frcp(x);
    return fmaf(r, fmaf(-x, r, 1.0f), r);
}

template <int CTRL>
__device__ __forceinline__ float dppx(float x) {
    return __int_as_float(__builtin_amdgcn_update_dpp(
        0, __float_as_int(x), CTRL, 0xF, 0xF, true));
}

__device__ __forceinline__ float bfly_sum(float x) {
    x += dppx<0xB1>(x);            // xor1 (quad_perm)
    x += dppx<0x4E>(x);            // xor2 (quad_perm)
    x += dppx<0x141>(x);           // xor4 (half_mirror)
    x += dppx<0x140>(x);           // xor8 (mirror)
    x += __shfl_xor(x, 16, 64);
    x += __shfl_xor(x, 32, 64);
    return x;
}
__device__ __forceinline__ float bfly_max(float x) {
    x = fmaxf(x, dppx<0xB1>(x));
    x = fmaxf(x, dppx<0x4E>(x));
    x = fmaxf(x, dppx<0x141>(x));
    x = fmaxf(x, dppx<0x140>(x));
    x = fmaxf(x, __shfl_xor(x, 16, 64));
    x = fmaxf(x, __shfl_xor(x, 32, 64));
    return x;
}

// accLo += f16lo(e2)*pLo ; accHi += f16hi(e2)*pHi  (one VALU op each)
__device__ __forceinline__ void fma_mix2(float& accLo, float& accHi, u32 e2,
                                         float pLo, float pHi) {
    asm("v_fma_mix_f32 %0, %2, %3, %0 op_sel_hi:[1,0,0]\n\t"
        "v_fma_mix_f32 %1, %2, %4, %1 op_sel:[1,0,0] op_sel_hi:[1,0,0]"
        : "+v"(accLo), "+v"(accHi)
        : "v"(e2), "v"(pLo), "v"(pHi));
}

// barrier draining LDS ops only — keeps global register-prefetch loads in flight
__device__ __forceinline__ void barrier_lgkm() {
    asm volatile("s_waitcnt lgkmcnt(0)\n\ts_barrier" ::: "memory");
}

// ---------------- Kernel A: E' = fp16(2^(M*CEXP+14)), stored transposed ----------------
__global__ __launch_bounds__(256)
void prep_exp_t(const float* __restrict__ X, float* __restrict__ out)
{
    const int blk  = blockIdx.x;
    const int b    = blk >> 4;
    const int tile = blk & 15;
    const int i0   = (tile >> 2) << 7;
    const int j0   = (tile & 3) << 7;
    const int tid  = threadIdx.x;

    const float* __restrict__ Mb = X + (size_t)b * (BN * BN);
    _Float16* __restrict__ Et = reinterpret_cast<_Float16*>(out + (size_t)b * (BN * BN));

    __shared__ _Float16 T[128][130];

    #pragma unroll
    for (int k = 0; k < 16; ++k) {
        int idx = tid + (k << 8);
        int fi  = idx >> 5;
        int fj  = idx & 31;
        float4 m = *reinterpret_cast<const float4*>(Mb + (size_t)(i0 + fi) * BN + j0 + (fj << 2));
        T[(fj << 2) + 0][fi] = (_Float16)fexp2(fmaf(m.x, CEXP, ESH));
        T[(fj << 2) + 1][fi] = (_Float16)fexp2(fmaf(m.y, CEXP, ESH));
        T[(fj << 2) + 2][fi] = (_Float16)fexp2(fmaf(m.z, CEXP, ESH));
        T[(fj << 2) + 3][fi] = (_Float16)fexp2(fmaf(m.w, CEXP, ESH));
    }
    __syncthreads();
    #pragma unroll
    for (int k = 0; k < 32; ++k) {
        int o  = tid + (k << 8);
        int j  = o >> 6;
        int c2 = o & 63;
        u32 val = *reinterpret_cast<const u32*>(&T[j][c2 << 1]);
        *reinterpret_cast<u32*>(Et + (size_t)(j0 + j) * BN + i0 + (c2 << 1)) = val;
    }
}

// ---------------- consume4 v4: linear-domain, plain frcp, no logs/NR/scales ------------
__device__ __forceinline__ void consume4v4(
    uint4 c0, uint4 c1, uint4 c2, uint4 c3, int jb,
    float pr0, float pr1, float pr2, float pr3,
    float pr4, float pr5, float pr6, float pr7,
    float& a0, float& a1, float& a2, float& a3,
    float& a4, float& a5, float& a6, float& a7,
    float& vml, const float* pbh, float* qv, int lane)
{
    const float4 pb4 = *reinterpret_cast<const float4*>(&pbh[jb]);

    float s00 = 0.f, s01 = 0.f;
    fma_mix2(s00, s01, c0.x, pr0, pr1); fma_mix2(s00, s01, c0.y, pr2, pr3);
    fma_mix2(s00, s01, c0.z, pr4, pr5); fma_mix2(s00, s01, c0.w, pr6, pr7);
    float s10 = 0.f, s11 = 0.f;
    fma_mix2(s10, s11, c1.x, pr0, pr1); fma_mix2(s10, s11, c1.y, pr2, pr3);
    fma_mix2(s10, s11, c1.z, pr4, pr5); fma_mix2(s10, s11, c1.w, pr6, pr7);
    float s20 = 0.f, s21 = 0.f;
    fma_mix2(s20, s21, c2.x, pr0, pr1); fma_mix2(s20, s21, c2.y, pr2, pr3);
    fma_mix2(s20, s21, c2.z, pr4, pr5); fma_mix2(s20, s21, c2.w, pr6, pr7);
    float s30 = 0.f, s31 = 0.f;
    fma_mix2(s30, s31, c3.x, pr0, pr1); fma_mix2(s30, s31, c3.y, pr2, pr3);
    fma_mix2(s30, s31, c3.z, pr4, pr5); fma_mix2(s30, s31, c3.w, pr6, pr7);

    float r0 = bfly_sum(s00 + s01);
    float r1 = bfly_sum(s10 + s11);
    float r2 = bfly_sum(s20 + s21);
    float r3 = bfly_sum(s30 + s31);

    // qr_j = 1/S_j (raw; carries the 2^14 and 2^beta scales implicitly)
    float q0 = frcp(r0), q1 = frcp(r1), q2 = frcp(r2), q3 = frcp(r3);

    // |v_j| * 2^-14 = pbh_j * qr_j  -> compare vs TAU_V
    vml = fmaxf(vml, fmaxf(fmaxf(pb4.x * q0, pb4.y * q1),
                           fmaxf(pb4.z * q2, pb4.w * q3)));
    if (lane == 0)
        *reinterpret_cast<float4*>(&qv[jb]) = make_float4(q0, q1, q2, q3);

    fma_mix2(a0, a1, c0.x, q0, q0); fma_mix2(a2, a3, c0.y, q0, q0);
    fma_mix2(a4, a5, c0.z, q0, q0); fma_mix2(a6, a7, c0.w, q0, q0);
    fma_mix2(a0, a1, c1.x, q1, q1); fma_mix2(a2, a3, c1.y, q1, q1);
    fma_mix2(a4, a5, c1.z, q1, q1); fma_mix2(a6, a7, c1.w, q1, q1);
    fma_mix2(a0, a1, c2.x, q2, q2); fma_mix2(a2, a3, c2.y, q2, q2);
    fma_mix2(a4, a5, c2.z, q2, q2); fma_mix2(a6, a7, c2.w, q2, q2);
    fma_mix2(a0, a1, c3.x, q3, q3); fma_mix2(a2, a3, c3.y, q3, q3);
    fma_mix2(a4, a5, c3.z, q3, q3); fma_mix2(a6, a7, c3.w, q3, q3);
}

// ---------------- Kernel B v4: linear diet on w512's EXACT 3-barrier skeleton ----------
// Invariants: pv = 2^alpha u (raw); 2^14 qv = 2^beta v; pah = 2^-alpha; pbh = 2^-beta.
__global__ __launch_bounds__(512)
__attribute__((amdgpu_waves_per_eu(2, 2)))
void sinkhorn_v4(const float* __restrict__ X, float* __restrict__ out,
                 float* __restrict__ cucv)
{
    const int b    = blockIdx.x;
    const int t    = threadIdx.x;      // 0..511
    const int lane = t & 63;
    const int w    = t >> 6;           // 0..7

    const u32* __restrict__ Et4 =
        reinterpret_cast<const u32*>(out + (size_t)b * (BN * BN));

    __shared__ float pah[BN], pbh[BN], pv[BN], qv[BN];   // 8 KB
    __shared__ float tpart[8][BN];                       // 16 KB
    __shared__ float wmaxlu[8], wmaxlv[8];
    __shared__ uint4 stage[8][16][64];                   // 128 KB -> 1 block/CU

    pah[t] = 1.0f; pbh[t] = 1.0f;
    pv[t]  = 0x1p-9f; qv[t] = 0x1p-9f;

    const int jb0 = w << 6;            // 64 columns per wave
    const u32* gbase = Et4 + (size_t)jb0 * 256 + (lane << 2);
#define LD(c) (*reinterpret_cast<const uint4*>(gbase + (size_t)(c) * 256))

    // static stage: cols jb0+48..jb0+63 (iteration-invariant, wave-private)
    #pragma unroll
    for (int c = 0; c < 16; ++c)
        stage[w][c][lane] = LD(48 + c);

    // proven 4-slot ring, 3-group lookahead
    uint4 e0 = LD(0),  e1 = LD(1),  e2 = LD(2),  e3 = LD(3);
    uint4 f0 = LD(4),  f1 = LD(5),  f2 = LD(6),  f3 = LD(7);
    uint4 h0 = LD(8),  h1 = LD(9),  h2 = LD(10), h3 = LD(11);
    uint4 k0, k1, k2, k3;

    __syncthreads();

    for (int it = 0; it < NITER; ++it) {
        const float4 prA = *reinterpret_cast<const float4*>(&pv[lane * 8]);
        const float4 prB = *reinterpret_cast<const float4*>(&pv[lane * 8 + 4]);
        const float pr0 = prA.x, pr1 = prA.y, pr2 = prA.z, pr3 = prA.w;
        const float pr4 = prB.x, pr5 = prB.y, pr6 = prB.z, pr7 = prB.w;

        float a0 = 0.f, a1 = 0.f, a2 = 0.f, a3 = 0.f;
        float a4 = 0.f, a5 = 0.f, a6 = 0.f, a7 = 0.f;
        float vml = 0.0f;

#define STEP(B0,B1,B2,B3, I0,I1,I2,I3, ICOL, JOFF)                            \
        I0 = LD((ICOL) + 0); I1 = LD((ICOL) + 1);                             \
        I2 = LD((ICOL) + 2); I3 = LD((ICOL) + 3);                             \
        consume4v4(B0, B1, B2, B3, jb0 + (JOFF),                              \
                   pr0, pr1, pr2, pr3, pr4, pr5, pr6, pr7,                    \
                   a0, a1, a2, a3, a4, a5, a6, a7, vml, pbh, qv, lane);

        STEP(e0,e1,e2,e3, k0,k1,k2,k3, 12,  0)
        STEP(f0,f1,f2,f3, e0,e1,e2,e3, 16,  4)
        STEP(h0,h1,h2,h3, f0,f1,f2,f3, 20,  8)
        STEP(k0,k1,k2,k3, h0,h1,h2,h3, 24, 12)
        STEP(e0,e1,e2,e3, k0,k1,k2,k3, 28, 16)
        STEP(f0,f1,f2,f3, e0,e1,e2,e3, 32, 20)
        STEP(h0,h1,h2,h3, f0,f1,f2,f3, 36, 24)
        STEP(k0,k1,k2,k3, h0,h1,h2,h3, 40, 28)
        STEP(e0,e1,e2,e3, k0,k1,k2,k3, 44, 32)
        STEP(f0,f1,f2,f3, e0,e1,e2,e3,  0, 36)
        STEP(h0,h1,h2,h3, f0,f1,f2,f3,  4, 40)
        STEP(k0,k1,k2,k3, h0,h1,h2,h3,  8, 44)
#undef STEP

        // 4 LDS groups: cols 48..63
        #pragma unroll
        for (int ls = 0; ls < 4; ++ls) {
            uint4 l0v = stage[w][ls * 4 + 0][lane];
            uint4 l1v = stage[w][ls * 4 + 1][lane];
            uint4 l2v = stage[w][ls * 4 + 2][lane];
            uint4 l3v = stage[w][ls * 4 + 3][lane];
            consume4v4(l0v, l1v, l2v, l3v, jb0 + 48 + ls * 4,
                       pr0, pr1, pr2, pr3, pr4, pr5, pr6, pr7,
                       a0, a1, a2, a3, a4, a5, a6, a7, vml, pbh, qv, lane);
        }

        *reinterpret_cast<float4*>(&tpart[w][lane * 8]) = make_float4(a0, a1, a2, a3);
        *reinterpret_cast<float4*>(&tpart[w][lane * 8 + 4]) = make_float4(a4, a5, a6, a7);
        if (lane == 0) wmaxlv[w] = vml;
        barrier_lgkm();                               // barrier 1

        // ---- fold: raw t, linear |u| check (no logs) ----
        float p0 = 0, p1 = 0, p2 = 0, p3 = 0;
        #pragma unroll
        for (int w2 = 0; w2 < 8; w2 += 4) {
            p0 += tpart[w2 + 0][t];
            p1 += tpart[w2 + 1][t];
            p2 += tpart[w2 + 2][t];
            p3 += tpart[w2 + 3][t];
        }
        float tt  = (p0 + p1) + (p2 + p3);
        float pvn = frcp(tt);                         // p_new = 1/t (raw)
        float ul  = pah[t] * pvn;                     // |u|
        float m   = bfly_max(ul);
        if (lane == 0) wmaxlu[w] = m;
        barrier_lgkm();                               // barrier 2

        float mlu = wmaxlu[0], mlv = wmaxlv[0];
        #pragma unroll
        for (int i2 = 1; i2 < 8; ++i2) {
            mlu = fmaxf(mlu, wmaxlu[i2]);
            mlv = fmaxf(mlv, wmaxlv[i2]);
        }
        if (mlu > TAU_U || mlv > TAU_V) {             // block-uniform
            pah[t] = frcp(pvn);                       // 2^-alpha_new = 1/p
            pv[t]  = pvn * 0x1p-9f;                   // p = 2^alpha_new / N
            float qo = qv[t];
            pbh[t] = 0x1p-14f * frcp(qo);             // 2^-beta_new = 2^-14/qr
            qv[t]  = qo * 0x1p-9f;                    // 2^14 q = 2^beta v, v = 1/N
        } else {
            pv[t] = pvn;
        }
        barrier_lgkm();                               // barrier 3 (unconditional)
    }
#undef LD

    // cu = log2(p); cv = 14 + log2(qr)
    cucv[(size_t)b * 1024 + t]       = flog2(pv[t]);
    cucv[(size_t)b * 1024 + 512 + t] = 14.0f + flog2(qv[t]);
}

// ---------------- consume4 v1 + fallback kernel: R10-proven verbatim ----------------
__device__ __forceinline__ void consume4(
    uint4 c0, uint4 c1, uint4 c2, uint4 c3, int jb,
    float pr0, float pr1, float pr2, float pr3,
    float pr4, float pr5, float pr6, float pr7,
    float& a0, float& a1, float& a2, float& a3,
    float& a4, float& a5, float& a6, float& a7,
    float& vml, const float* bh, float* lv, int lane)
{
    const float4 bh4 = *reinterpret_cast<const float4*>(&bh[jb]);

    float s00 = 0.f, s01 = 0.f;
    fma_mix2(s00, s01, c0.x, pr0, pr1); fma_mix2(s00, s01, c0.y, pr2, pr3);
    fma_mix2(s00, s01, c0.z, pr4, pr5); fma_mix2(s00, s01, c0.w, pr6, pr7);
    float s10 = 0.f, s11 = 0.f;
    fma_mix2(s10, s11, c1.x, pr0, pr1); fma_mix2(s10, s11, c1.y, pr2, pr3);
    fma_mix2(s10, s11, c1.z, pr4, pr5); fma_mix2(s10, s11, c1.w, pr6, pr7);
    float s20 = 0.f, s21 = 0.f;
    fma_mix2(s20, s21, c2.x, pr0, pr1); fma_mix2(s20, s21, c2.y, pr2, pr3);
    fma_mix2(s20, s21, c2.z, pr4, pr5); fma_mix2(s20, s21, c2.w, pr6, pr7);
    float s30 = 0.f, s31 = 0.f;
    fma_mix2(s30, s31, c3.x, pr0, pr1); fma_mix2(s30, s31, c3.y, pr2, pr3);
    fma_mix2(s30, s31, c3.z, pr4, pr5); fma_mix2(s30, s31, c3.w, pr6, pr7);

    float r0 = bfly_sum(s00 + s01);
    float r1 = bfly_sum(s10 + s11);
    float r2 = bfly_sum(s20 + s21);
    float r3 = bfly_sum(s30 + s31);

    float t0 = r0 * 0x1p-14f, t1 = r1 * 0x1p-14f;
    float t2 = r2 * 0x1p-14f, t3 = r3 * 0x1p-14f;
    float q0 = nr_rcp(t0), q1 = nr_rcp(t1), q2 = nr_rcp(t2), q3 = nr_rcp(t3);
    float l0 = -bh4.x - flog2(t0), l1 = -bh4.y - flog2(t1);
    float l2 = -bh4.z - flog2(t2), l3 = -bh4.w - flog2(t3);
    vml = fmaxf(vml, fmaxf(fmaxf(l0, l1), fmaxf(l2, l3)));
    if (lane == 0)
        *reinterpret_cast<float4*>(&lv[jb]) = make_float4(l0, l1, l2, l3);

    fma_mix2(a0, a1, c0.x, q0, q0); fma_mix2(a2, a3, c0.y, q0, q0);
    fma_mix2(a4, a5, c0.z, q0, q0); fma_mix2(a6, a7, c0.w, q0, q0);
    fma_mix2(a0, a1, c1.x, q1, q1); fma_mix2(a2, a3, c1.y, q1, q1);
    fma_mix2(a4, a5, c1.z, q1, q1); fma_mix2(a6, a7, c1.w, q1, q1);
    fma_mix2(a0, a1, c2.x, q2, q2); fma_mix2(a2, a3, c2.y, q2, q2);
    fma_mix2(a4, a5, c2.z, q2, q2); fma_mix2(a6, a7, c2.w, q2, q2);
    fma_mix2(a0, a1, c3.x, q3, q3); fma_mix2(a2, a3, c3.y, q3, q3);
    fma_mix2(a4, a5, c3.z, q3, q3); fma_mix2(a6, a7, c3.w, q3, q3);
}

__global__ __launch_bounds__(512)
__attribute__((amdgpu_waves_per_eu(2, 2)))
void sinkhorn_w512(const float* __restrict__ X, float* __restrict__ out,
                   float* __restrict__ cucv)
{
    const int b    = blockIdx.x;
    const int t    = threadIdx.x;
    const int lane = t & 63;
    const int w    = t >> 6;

    const u32* __restrict__ Et4 =
        reinterpret_cast<const u32*>(out + (size_t)b * (BN * BN));

    __shared__ float ah[BN], bh[BN], lu[BN], lv[BN], pv[BN];
    __shared__ float tpart[8][BN];
    __shared__ float wmaxlu[8], wmaxlv[8];
    __shared__ uint4 stage[8][16][64];

    ah[t] = 0.f; bh[t] = 0.f;
    lu[t] = -9.f; lv[t] = -9.f;
    pv[t] = 0x1p-9f;

    const int jb0 = w << 6;
    const u32* gbase = Et4 + (size_t)jb0 * 256 + (lane << 2);
#define LD(c) (*reinterpret_cast<const uint4*>(gbase + (size_t)(c) * 256))

    #pragma unroll
    for (int c = 0; c < 16; ++c)
        stage[w][c][lane] = LD(48 + c);

    uint4 e0 = LD(0),  e1 = LD(1),  e2 = LD(2),  e3 = LD(3);
    uint4 f0 = LD(4),  f1 = LD(5),  f2 = LD(6),  f3 = LD(7);
    uint4 h0 = LD(8),  h1 = LD(9),  h2 = LD(10), h3 = LD(11);
    uint4 k0, k1, k2, k3;

    __syncthreads();

    for (int it = 0; it < NITER; ++it) {
        const float4 prA = *reinterpret_cast<const float4*>(&pv[lane * 8]);
        const float4 prB = *reinterpret_cast<const float4*>(&pv[lane * 8 + 4]);
        const float pr0 = prA.x, pr1 = prA.y, pr2 = prA.z, pr3 = prA.w;
        const float pr4 = prB.x, pr5 = prB.y, pr6 = prB.z, pr7 = prB.w;

        float a0 = 0.f, a1 = 0.f, a2 = 0.f, a3 = 0.f;
        float a4 = 0.f, a5 = 0.f, a6 = 0.f, a7 = 0.f;
        float vml = -1e30f;

#define STEP(B0,B1,B2,B3, I0,I1,I2,I3, ICOL, JOFF)                            \
        I0 = LD((ICOL) + 0); I1 = LD((ICOL) + 1);                             \
        I2 = LD((ICOL) + 2); I3 = LD((ICOL) + 3);                             \
        consume4(B0, B1, B2, B3, jb0 + (JOFF),                                \
                 pr0, pr1, pr2, pr3, pr4, pr5, pr6, pr7,                      \
                 a0, a1, a2, a3, a4, a5, a6, a7, vml, bh, lv, lane);

        STEP(e0,e1,e2,e3, k0,k1,k2,k3, 12,  0)
        STEP(f0,f1,f2,f3, e0,e1,e2,e3, 16,  4)
        STEP(h0,h1,h2,h3, f0,f1,f2,f3, 20,  8)
        STEP(k0,k1,k2,k3, h0,h1,h2,h3, 24, 12)
        STEP(e0,e1,e2,e3, k0,k1,k2,k3, 28, 16)
        STEP(f0,f1,f2,f3, e0,e1,e2,e3, 32, 20)
        STEP(h0,h1,h2,h3, f0,f1,f2,f3, 36, 24)
        STEP(k0,k1,k2,k3, h0,h1,h2,h3, 40, 28)
        STEP(e0,e1,e2,e3, k0,k1,k2,k3, 44, 32)
        STEP(f0,f1,f2,f3, e0,e1,e2,e3,  0, 36)
        STEP(h0,h1,h2,h3, f0,f1,f2,f3,  4, 40)
        STEP(k0,k1,k2,k3, h0,h1,h2,h3,  8, 44)
#undef STEP

        #pragma unroll
        for (int ls = 0; ls < 4; ++ls) {
            uint4 l0v = stage[w][ls * 4 + 0][lane];
            uint4 l1v = stage[w][ls * 4 + 1][lane];
            uint4 l2v = stage[w][ls * 4 + 2][lane];
            uint4 l3v = stage[w][ls * 4 + 3][lane];
            consume4(l0v, l1v, l2v, l3v, jb0 + 48 + ls * 4,
                     pr0, pr1, pr2, pr3, pr4, pr5, pr6, pr7,
                     a0, a1, a2, a3, a4, a5, a6, a7, vml, bh, lv, lane);
        }

        *reinterpret_cast<float4*>(&tpart[w][lane * 8]) = make_float4(a0, a1, a2, a3);
        *reinterpret_cast<float4*>(&tpart[w][lane * 8 + 4]) = make_float4(a4, a5, a6, a7);
        if (lane == 0) wmaxlv[w] = vml;
        barrier_lgkm();

        float p0 = 0, p1 = 0, p2 = 0, p3 = 0;
        #pragma unroll
        for (int w2 = 0; w2 < 8; w2 += 4) {
            p0 += tpart[w2 + 0][t];
            p1 += tpart[w2 + 1][t];
            p2 += tpart[w2 + 2][t];
            p3 += tpart[w2 + 3][t];
        }
        float tt  = ((p0 + p1) + (p2 + p3)) * 0x1p-14f;
        float lun = -ah[t] - flog2(tt);
        float m = bfly_max(lun);
        if (lane == 0) wmaxlu[w] = m;
        barrier_lgkm();

        float mlu = wmaxlu[0], mlv = wmaxlv[0];
        #pragma unroll
        for (int i2 = 1; i2 < 8; ++i2) {
            mlu = fmaxf(mlu, wmaxlu[i2]);
            mlv = fmaxf(mlv, wmaxlv[i2]);
        }
        if (mlu > L2TAU || mlv > L2TAU) {
            float an = ah[t] + lun;
            ah[t] = an;
            lu[t] = -9.f;
            pv[t] = fexp2(an - 9.0f);
            bh[t] += lv[t];
            lv[t] = -9.f;
        } else {
            lu[t] = lun;
            pv[t] = nr_rcp(tt);
        }
        barrier_lgkm();
    }
#undef LD

    cucv[(size_t)b * 1024 + t]       = ah[t] + lu[t];
    cucv[(size_t)b * 1024 + 512 + t] = bh[t] + lv[t];
}

// ---------------- Kernel C: Gamma epilogue on the full chip ----------------
__global__ __launch_bounds__(256)
void gamma_out(const float* __restrict__ X, float* __restrict__ out,
               const float* __restrict__ cucv)
{
    const int blk  = blockIdx.x;
    const int b    = blk >> 4;
    const int tile = blk & 15;
    const int tid  = threadIdx.x;
    const int i0   = tile << 5;

    __shared__ float cu[32];
    __shared__ float cv[BN];

    if (tid < 32) cu[tid] = cucv[(size_t)b * 1024 + i0 + tid];
    cv[tid]        = cucv[(size_t)b * 1024 + 512 + tid];
    cv[tid + 256]  = cucv[(size_t)b * 1024 + 768 + tid];
    __syncthreads();

    const float* __restrict__ Mb = X + (size_t)b * (BN * BN);
    float* __restrict__ Gb = out + (size_t)b * (BN * BN);
    const float4* __restrict__ cv4 = reinterpret_cast<const float4*>(cv);

    #pragma unroll
    for (int k = 0; k < 16; ++k) {
        int idx = tid + (k << 8);
        int r   = idx >> 7;
        int c4  = idx & 127;
        int i   = i0 + r;
        float4 m = *reinterpret_cast<const float4*>(Mb + (size_t)i * BN + (c4 << 2));
        float4 c = cv4[c4];
        float cui = cu[r];
        float4 g;
        g.x = fexp2(fmaf(m.x, CEXP, cui + c.x));
        g.y = fexp2(fmaf(m.y, CEXP, cui + c.y));
        g.z = fexp2(fmaf(m.z, CEXP, cui + c.z));
        g.w = fexp2(fmaf(m.w, CEXP, cui + c.w));
        *reinterpret_cast<float4*>(Gb + (size_t)i * BN + (c4 << 2)) = g;
    }
}

extern "C" void kernel_launch(void* const* d_in, const int* in_sizes, int n_in,
                              void* d_out, int out_size, void* d_ws, size_t ws_size,
                              hipStream_t stream)
{
    const float* X = (const float*)d_in[0];
    float* out = (float*)d_out;
    const int batch = in_sizes[0] / (BN * BN);   // 128

    prep_exp_t<<<batch * 16, 256, 0, stream>>>(X, out);

    // spill guard only: scratch-free v4 is safe at any register count
    bool v4_ok = false;
    hipFuncAttributes fa{};
    if (hipFuncGetAttributes(&fa, (const void*)sinkhorn_v4) == hipSuccess)
        v4_ok = (fa.localSizeBytes == 0);

    float* cucv = (float*)d_ws;
    if (v4_ok)
        sinkhorn_v4<<<batch, 512, 0, stream>>>(X, out, cucv);
    else
        sinkhorn_w512<<<batch, 512, 0, stream>>>(X, out, cucv);
    gamma_out<<<batch * 16, 256, 0, stream>>>(X, out, cucv);
}